// Round 1
// baseline (1774.442 us; speedup 1.0000x reference)
//
#include <hip/hip_runtime.h>

// AR LSTM decoder, B=256, T=2048, IN=64, H=32, NCLS=5.
//
// R5 restructure: decouple the x-projection from the serial recurrence.
//   Kernel 1 (gx_gemm): gx[b*T+t][r] = W_ih[r,0:64]·x[b,t] + b_ih[r] + b_hh[r]
//     for all 524288 rows — pure throughput, identical accumulation order to
//     the old producer wave (bit-identical gx values).
//   Kernel 2 (ar_decode_pre): ONE wave per batch row. The proven consumer
//     math verbatim; gate inputs streamed global->VGPR with a 16-step
//     register ping-pong (all static indices — no scratch), one group of
//     loads always in flight. No producer wave, no LDS flags, no spinning,
//     no VGPR pressure (~220/512 at 1 wave/SIMD).
// Falls back to the old fused kernel when ws_size < 256 MB.

namespace {

typedef float f2 __attribute__((ext_vector_type(2)));
typedef unsigned int u32;
typedef const __attribute__((address_space(1))) u32* gas_ptr;
typedef __attribute__((address_space(3))) u32* las_ptr;

constexpr int Tn  = 2048;
constexpr int INn = 64;
constexpr int Hn  = 32;
constexpr int NC  = 5;
constexpr int Bn  = 256;
constexpr int BT  = Bn * Tn;       // 524288 x-rows
constexpr int Gp  = 16;            // decode prefetch group (steps)
constexpr int NG  = Tn / Gp;       // 128 groups

// old fused kernel's constants
constexpr int CH  = 32;            // steps per chunk
constexpr int CHF = CH * INn;      // 2048 floats x-chunk (8 KB)
constexpr int GXF = CH * 128;      // 4096 floats gx-chunk (16 KB)
constexpr int NCHUNK = Tn / CH;    // 64

__device__ __forceinline__ float rcpf(float x) { return __builtin_amdgcn_rcpf(x); }
__device__ __forceinline__ float hadd(f2 v) { return v.x + v.y; }

template <int CTRL, int RM, int BM, bool BC>
__device__ __forceinline__ float dpp_add(float x) {
    int t = __builtin_amdgcn_update_dpp(0, __float_as_int(x), CTRL, RM, BM, BC);
    return x + __int_as_float(t);
}

// sum over all 64 lanes, result broadcast via readlane(63)  [proven in R2]
__device__ __forceinline__ float wave_sum64(float x) {
    x = dpp_add<0x111, 0xF, 0xF, true>(x);   // row_shr:1
    x = dpp_add<0x112, 0xF, 0xF, true>(x);   // row_shr:2
    x = dpp_add<0x114, 0xF, 0xF, true>(x);   // row_shr:4
    x = dpp_add<0x118, 0xF, 0xF, true>(x);   // row_shr:8
    x = dpp_add<0x142, 0xA, 0xF, false>(x);  // row_bcast15
    x = dpp_add<0x143, 0xC, 0xF, false>(x);  // row_bcast31 -> lane 63 total
    return __int_as_float(__builtin_amdgcn_readlane(__float_as_int(x), 63));
}

__device__ __forceinline__ float dpp_swap1(float x) {   // quad_perm xor 1
    int t = __builtin_amdgcn_update_dpp(0, __float_as_int(x), 0xB1, 0xF, 0xF, true);
    return __int_as_float(t);
}

__device__ __forceinline__ void gl16(const float* g, float* l) {
    __builtin_amdgcn_global_load_lds((gas_ptr)g, (las_ptr)l, 16, 0, 0);
}

__device__ __forceinline__ int ld_acq(int* p) {
    return __hip_atomic_load(p, __ATOMIC_ACQUIRE, __HIP_MEMORY_SCOPE_WORKGROUP);
}
__device__ __forceinline__ void st_rel(int* p, int v) {
    __hip_atomic_store(p, v, __ATOMIC_RELEASE, __HIP_MEMORY_SCOPE_WORKGROUP);
}

// =====================================================================
// Kernel 1: x-projection GEMM. Lane owns gate rows (lane, lane+64); the
// x row address is wave-uniform (readfirstlane-pinned -> scalar loads).
// Accumulation order copied verbatim from the old producer wave.
__global__ __launch_bounds__(256, 2)
void gx_gemm(const float* __restrict__ x,
             const float* __restrict__ W_ih,
             const float* __restrict__ b_ih,
             const float* __restrict__ b_hh,
             float* __restrict__ gx)
{
    const int lane = threadIdx.x & 63;
    const int wid  = blockIdx.x * 4 + (threadIdx.x >> 6);
    const int nw   = gridDim.x * 4;

    f2 wA[INn / 2], wB[INn / 2];    // 128 VGPR — volatile-pinned (R2/R3 lesson)
    {
        const volatile f2* pA = (const volatile f2*)(W_ih + (size_t)lane * 2 * INn);
        const volatile f2* pB = (const volatile f2*)(W_ih + (size_t)(lane + 64) * 2 * INn);
        #pragma unroll
        for (int i = 0; i < INn / 2; ++i) { wA[i] = pA[i]; wB[i] = pB[i]; }
    }
    const float biasA = b_ih[lane] + b_hh[lane];
    const float biasB = b_ih[lane + 64] + b_hh[lane + 64];

    for (int row0 = wid; row0 < BT; row0 += nw) {
        const int row = __builtin_amdgcn_readfirstlane(row0);
        const f2* xr = (const f2*)(x + (size_t)row * INn);
        f2 a0, a1, a2, a3, c0, c1, c2, c3;
        a0 = a1 = a2 = a3 = c0 = c1 = c2 = c3 = (f2)(0.f);
        #pragma unroll
        for (int i = 0; i < INn / 2; i += 4) {
            const f2 x0 = xr[i], x1 = xr[i + 1], x2 = xr[i + 2], x3 = xr[i + 3];
            a0 += wA[i] * x0;     c0 += wB[i] * x0;
            a1 += wA[i + 1] * x1; c1 += wB[i + 1] * x1;
            a2 += wA[i + 2] * x2; c2 += wB[i + 2] * x2;
            a3 += wA[i + 3] * x3; c3 += wB[i + 3] * x3;
        }
        float* o = gx + (size_t)row * 128;
        o[lane]      = biasA + hadd((a0 + a1) + (a2 + a3));
        o[lane + 64] = biasB + hadd((c0 + c1) + (c2 + c3));
    }
}

// =====================================================================
// Kernel 2: serial recurrence, 1 wave per batch row. Consumer math verbatim
// from the proven kernel; gx streamed from global with register ping-pong.
__global__ __launch_bounds__(64, 1)
void ar_decode_pre(const float* __restrict__ gx,
                   const float* __restrict__ W_ih,
                   const float* __restrict__ W_hh,
                   const float* __restrict__ W_fc,
                   const float* __restrict__ b_fc,
                   const float* __restrict__ emb,
                   float* __restrict__ out)
{
    const int b    = blockIdx.x;
    const int lane = threadIdx.x & 63;
    const int m    = lane >> 1;
    const int par  = lane & 1;
    const bool even = (par == 0);
    const int rA = par * Hn + m;            // i-row (par0) or f-row (par1)
    // rB = rA + 64: g-row (par0) or o-row (par1)

    __shared__ float s_h[Hn];
    if (lane < Hn) s_h[lane] = 0.f;         // single wave: in-order LDS, no barrier

    f2 whA[Hn / 2], whB[Hn / 2];            // 64 VGPR — volatile-pinned
    {
        const volatile f2* pA = (const volatile f2*)(W_hh + (size_t)rA * Hn);
        const volatile f2* pB = (const volatile f2*)(W_hh + (size_t)(rA + 2 * Hn) * Hn);
        #pragma unroll
        for (int i = 0; i < Hn / 2; ++i) { whA[i] = pA[i]; whB[i] = pB[i]; }
    }

    // P[cls] = ( dot(W_ih[rA,64:128], emb[cls]), dot(W_ih[rB,64:128], emb[cls]) )
    f2 P[NC];
    #pragma unroll
    for (int cls = 0; cls < NC; ++cls) {
        float pa = 0.f, pb = 0.f;
        for (int i = 0; i < INn; ++i) {
            const float e = emb[cls * INn + i];
            pa += W_ih[(size_t)rA * 2 * INn + INn + i] * e;
            pb += W_ih[(size_t)(rA + 2 * Hn) * 2 * INn + INn + i] * e;
        }
        f2 v; v.x = pa; v.y = pb; P[cls] = v;
    }

    // classifier: lane holds 0.5*W_fc[cls][m] (h duplicated on parities)
    const float wfc0 = 0.5f * W_fc[0 * Hn + m];
    const float wfc1 = 0.5f * W_fc[1 * Hn + m];
    const float wfc2 = 0.5f * W_fc[2 * Hn + m];
    const float wfc3 = 0.5f * W_fc[3 * Hn + m];
    const float wfc4 = 0.5f * W_fc[4 * Hn + m];
    const float bf0 = b_fc[0], bf1 = b_fc[1], bf2 = b_fc[2],
                bf3 = b_fc[3], bf4 = b_fc[4];

    const float zsB  = even ? 2.f : 1.f;    // g: tanh(z) = 2*sig(2z)-1
    const float mulB = even ? 2.f : 1.f;
    const float addB = even ? -1.f : 0.f;

    const float* __restrict__ gxb = gx + (size_t)b * Tn * 128;
    float* __restrict__ ob = out + (size_t)b * Tn * NC;

    float c = 0.f;
    f2 Ps; Ps.x = 0.f; Ps.y = 0.f;

    // ---- 16-step register ping-pong prefetch of (gA, gB) ----
    float aX[Gp], bX[Gp], aY[Gp], bY[Gp];

    auto loadg = [&](float* A, float* Bv, int g) {
        const float* p = gxb + (size_t)g * Gp * 128;
        #pragma unroll
        for (int j = 0; j < Gp; ++j) {
            A[j]  = p[j * 128 + rA];
            Bv[j] = p[j * 128 + rA + 64];
        }
    };

    auto step = [&](float gA, float gB, int t) {
        // h broadcast from LDS (previous step's h)
        const f2* h2 = (const f2*)s_h;
        f2 hv[Hn / 2];
        #pragma unroll
        for (int i = 0; i < Hn / 2; ++i) hv[i] = h2[i];

        // W_hh · h (4 chains per row) — order identical to proven kernel
        f2 aA0, aA1, aA2, aA3, aB0, aB1, aB2, aB3;
        aA0 = aA1 = aA2 = aA3 = aB0 = aB1 = aB2 = aB3 = (f2)(0.f);
        #pragma unroll
        for (int i = 0; i < Hn / 2; i += 4) {
            const f2 h0 = hv[i], h1 = hv[i + 1], h3 = hv[i + 2], h4 = hv[i + 3];
            aA0 += whA[i] * h0;     aB0 += whB[i] * h0;
            aA1 += whA[i + 1] * h1; aB1 += whB[i + 1] * h1;
            aA2 += whA[i + 2] * h3; aB2 += whB[i + 2] * h3;
            aA3 += whA[i + 3] * h4; aB3 += whB[i + 3] * h4;
        }
        const float accA = gA + hadd((aA0 + aA1) + (aA2 + aA3)) + Ps.x;
        const float accB = gB + hadd((aB0 + aB1) + (aB2 + aB3)) + Ps.y;

        // activations: A = sigmoid (i/f); B = tanh (g) / sigmoid (o)
        const float actA = rcpf(1.f + __expf(-accA));
        const float sgB  = rcpf(1.f + __expf(-zsB * accB));
        const float actB = fmaf(sgB, mulB, addB);

        // pair exchange (xor 1)
        const float qA = dpp_swap1(actA);
        const float qB = dpp_swap1(actB);
        const float iv = even ? actA : qA;
        const float fv = even ? qA : actA;
        const float gv = even ? actB : qB;
        const float ov = even ? qB : actB;

        // cell update (redundant in both parities -> identical)
        c = fmaf(fv, c, iv * gv);
        const float e2 = __expf(2.f * c);
        const float th = 1.f - 2.f * rcpf(e2 + 1.f);
        const float h  = ov * th;
        if (even) s_h[m] = h;     // next step's matvec input

        // logits from the fresh in-register h
        float p0 = wave_sum64(h * wfc0) + bf0;
        float p1 = wave_sum64(h * wfc1) + bf1;
        float p2 = wave_sum64(h * wfc2) + bf2;
        float p3 = wave_sum64(h * wfc3) + bf3;
        float p4 = wave_sum64(h * wfc4) + bf4;

        // argmax (first-max-wins, matches np.argmax)
        int am = 0; float bv = p0;
        if (p1 > bv) { bv = p1; am = 1; }
        if (p2 > bv) { bv = p2; am = 2; }
        if (p3 > bv) { bv = p3; am = 3; }
        if (p4 > bv) { bv = p4; am = 4; }

        // next-step prev-embedding contribution
        Ps = (am == 0) ? P[0] : (am == 1) ? P[1] : (am == 2) ? P[2]
           : (am == 3) ? P[3] : P[4];

        // log-softmax + store (off-chain)
        const float se = __expf(p0 - bv) + __expf(p1 - bv) + __expf(p2 - bv)
                       + __expf(p3 - bv) + __expf(p4 - bv);
        const float lse = bv + __logf(se);
        if (lane < NC) {
            float pv = p0;
            pv = (lane == 1) ? p1 : pv;
            pv = (lane == 2) ? p2 : pv;
            pv = (lane == 3) ? p3 : pv;
            pv = (lane == 4) ? p4 : pv;
            ob[(size_t)t * NC + lane] = pv - lse;
        }
    };

    loadg(aX, bX, 0);
    loadg(aY, bY, 1);

    for (int gp = 0; gp < NG; gp += 2) {
        #pragma unroll
        for (int j = 0; j < Gp; ++j) step(aX[j], bX[j], gp * Gp + j);
        if (gp + 2 < NG) loadg(aX, bX, gp + 2);      // in flight during Y compute
        #pragma unroll
        for (int j = 0; j < Gp; ++j) step(aY[j], bY[j], (gp + 1) * Gp + j);
        if (gp + 3 < NG) loadg(aY, bY, gp + 3);      // in flight during next X
    }
}

// =====================================================================
// Fallback: previous fused 2-wave kernel (unchanged), used when the
// workspace cannot hold gx.
__global__ __launch_bounds__(128, 1)
void ar_decode(const float* __restrict__ x,
               const float* __restrict__ W_ih,
               const float* __restrict__ W_hh,
               const float* __restrict__ b_ih,
               const float* __restrict__ b_hh,
               const float* __restrict__ W_fc,
               const float* __restrict__ b_fc,
               const float* __restrict__ emb,
               float* __restrict__ out)
{
    const int b    = blockIdx.x;
    const int tid  = threadIdx.x;
    const int lane = tid & 63;
    const int m    = lane >> 1;
    const int par  = lane & 1;
    const bool even = (par == 0);
    const int rA = par * Hn + m;
    const int rB = 2 * Hn + par * Hn + m;

    __shared__ __align__(16) float s_xp[2 * CHF];
    __shared__ __align__(16) float s_gx[2 * GXF];
    __shared__ __align__(16) float s_h[Hn];
    __shared__ int s_prog;
    __shared__ int s_cons;

    if (tid == 0) { s_prog = 0; s_cons = 0; }
    if (tid < Hn) s_h[tid] = 0.f;
    __syncthreads();

    const float* __restrict__ xb = x + (size_t)b * Tn * INn;

    if (tid >= 64) {
        f2 wA[INn / 2], wB[INn / 2];
        {
            const volatile f2* pA = (const volatile f2*)(W_ih + (size_t)rA * 2 * INn);
            const volatile f2* pB = (const volatile f2*)(W_ih + (size_t)rB * 2 * INn);
            #pragma unroll
            for (int i = 0; i < INn / 2; ++i) { wA[i] = pA[i]; wB[i] = pB[i]; }
        }
        const float biasA = b_ih[rA] + b_hh[rA];
        const float biasB = b_ih[rB] + b_hh[rB];

        #pragma unroll
        for (int r = 0; r < 8; ++r) gl16(xb + r * 256 + lane * 4, s_xp + r * 256);
        #pragma unroll
        for (int r = 0; r < 8; ++r) gl16(xb + CHF + r * 256 + lane * 4, s_xp + CHF + r * 256);

        for (int q = 0; q < NCHUNK; ++q) {
            if (q == NCHUNK - 1) asm volatile("s_waitcnt vmcnt(0)" ::: "memory");
            else                 asm volatile("s_waitcnt vmcnt(8)" ::: "memory");
            while (ld_acq(&s_cons) < q - 1) { }

            const f2* xc  = (const f2*)(s_xp + (q & 1) * CHF);
            float*    gxd = s_gx + (q & 1) * GXF;
            #pragma unroll 2
            for (int s = 0; s < CH; ++s) {
                const f2* xt2 = xc + s * (INn / 2);
                f2 a0, a1, a2, a3, c0, c1, c2, c3;
                a0 = a1 = a2 = a3 = c0 = c1 = c2 = c3 = (f2)(0.f);
                #pragma unroll
                for (int i = 0; i < INn / 2; i += 4) {
                    const f2 x0 = xt2[i], x1 = xt2[i + 1], x2 = xt2[i + 2], x3 = xt2[i + 3];
                    a0 += wA[i] * x0;     c0 += wB[i] * x0;
                    a1 += wA[i + 1] * x1; c1 += wB[i + 1] * x1;
                    a2 += wA[i + 2] * x2; c2 += wB[i + 2] * x2;
                    a3 += wA[i + 3] * x3; c3 += wB[i + 3] * x3;
                }
                gxd[s * 128 + rA] = biasA + hadd((a0 + a1) + (a2 + a3));
                gxd[s * 128 + rB] = biasB + hadd((c0 + c1) + (c2 + c3));
            }
            if (lane == 0) st_rel(&s_prog, q + 1);
            if (q + 2 < NCHUNK) {
                const float* src = xb + (size_t)(q + 2) * CHF;
                float* dst = s_xp + (q & 1) * CHF;
                #pragma unroll
                for (int r = 0; r < 8; ++r) gl16(src + r * 256 + lane * 4, dst + r * 256);
            }
        }
    } else {
        f2 whA[Hn / 2], whB[Hn / 2];
        {
            const volatile f2* pA = (const volatile f2*)(W_hh + (size_t)rA * Hn);
            const volatile f2* pB = (const volatile f2*)(W_hh + (size_t)rB * Hn);
            #pragma unroll
            for (int i = 0; i < Hn / 2; ++i) { whA[i] = pA[i]; whB[i] = pB[i]; }
        }

        f2 P[NC];
        #pragma unroll
        for (int cls = 0; cls < NC; ++cls) {
            float pa = 0.f, pb = 0.f;
            for (int i = 0; i < INn; ++i) {
                const float e = emb[cls * INn + i];
                pa += W_ih[(size_t)rA * 2 * INn + INn + i] * e;
                pb += W_ih[(size_t)rB * 2 * INn + INn + i] * e;
            }
            f2 v; v.x = pa; v.y = pb; P[cls] = v;
        }

        const float wfc0 = 0.5f * W_fc[0 * Hn + m];
        const float wfc1 = 0.5f * W_fc[1 * Hn + m];
        const float wfc2 = 0.5f * W_fc[2 * Hn + m];
        const float wfc3 = 0.5f * W_fc[3 * Hn + m];
        const float wfc4 = 0.5f * W_fc[4 * Hn + m];
        const float bf0 = b_fc[0], bf1 = b_fc[1], bf2 = b_fc[2],
                    bf3 = b_fc[3], bf4 = b_fc[4];

        const float zsB  = even ? 2.f : 1.f;
        const float mulB = even ? 2.f : 1.f;
        const float addB = even ? -1.f : 0.f;

        float* __restrict__ ob = out + (size_t)b * Tn * NC;

        float c = 0.f;
        f2 Ps; Ps.x = 0.f; Ps.y = 0.f;

        for (int q = 0; q < NCHUNK; ++q) {
            while (ld_acq(&s_prog) < q + 1) { }
            const float* gxc = s_gx + (q & 1) * GXF;

            #pragma unroll 2
            for (int s = 0; s < CH; ++s) {
                const float gA = gxc[s * 128 + rA];
                const float gB = gxc[s * 128 + rB];

                const f2* h2 = (const f2*)s_h;
                f2 hv[Hn / 2];
                #pragma unroll
                for (int i = 0; i < Hn / 2; ++i) hv[i] = h2[i];

                f2 aA0, aA1, aA2, aA3, aB0, aB1, aB2, aB3;
                aA0 = aA1 = aA2 = aA3 = aB0 = aB1 = aB2 = aB3 = (f2)(0.f);
                #pragma unroll
                for (int i = 0; i < Hn / 2; i += 4) {
                    const f2 h0 = hv[i], h1 = hv[i + 1], h3 = hv[i + 2], h4 = hv[i + 3];
                    aA0 += whA[i] * h0;     aB0 += whB[i] * h0;
                    aA1 += whA[i + 1] * h1; aB1 += whB[i + 1] * h1;
                    aA2 += whA[i + 2] * h3; aB2 += whB[i + 2] * h3;
                    aA3 += whA[i + 3] * h4; aB3 += whB[i + 3] * h4;
                }
                const float accA = gA + hadd((aA0 + aA1) + (aA2 + aA3)) + Ps.x;
                const float accB = gB + hadd((aB0 + aB1) + (aB2 + aB3)) + Ps.y;

                const float actA = rcpf(1.f + __expf(-accA));
                const float sgB  = rcpf(1.f + __expf(-zsB * accB));
                const float actB = fmaf(sgB, mulB, addB);

                const float qA = dpp_swap1(actA);
                const float qB = dpp_swap1(actB);
                const float iv = even ? actA : qA;
                const float fv = even ? qA : actA;
                const float gv = even ? actB : qB;
                const float ov = even ? qB : actB;

                c = fmaf(fv, c, iv * gv);
                const float e2 = __expf(2.f * c);
                const float th = 1.f - 2.f * rcpf(e2 + 1.f);
                const float h  = ov * th;
                if (even) s_h[m] = h;

                float p0 = wave_sum64(h * wfc0) + bf0;
                float p1 = wave_sum64(h * wfc1) + bf1;
                float p2 = wave_sum64(h * wfc2) + bf2;
                float p3 = wave_sum64(h * wfc3) + bf3;
                float p4 = wave_sum64(h * wfc4) + bf4;

                int am = 0; float bv = p0;
                if (p1 > bv) { bv = p1; am = 1; }
                if (p2 > bv) { bv = p2; am = 2; }
                if (p3 > bv) { bv = p3; am = 3; }
                if (p4 > bv) { bv = p4; am = 4; }

                Ps = (am == 0) ? P[0] : (am == 1) ? P[1] : (am == 2) ? P[2]
                   : (am == 3) ? P[3] : P[4];

                const float se = __expf(p0 - bv) + __expf(p1 - bv) + __expf(p2 - bv)
                               + __expf(p3 - bv) + __expf(p4 - bv);
                const float lse = bv + __logf(se);
                if (lane < NC) {
                    float pv = p0;
                    pv = (lane == 1) ? p1 : pv;
                    pv = (lane == 2) ? p2 : pv;
                    pv = (lane == 3) ? p3 : pv;
                    pv = (lane == 4) ? p4 : pv;
                    ob[(size_t)(q * CH + s) * NC + lane] = pv - lse;
                }
            }
            if (lane == 0) st_rel(&s_cons, q + 1);
        }
    }
}

} // namespace

extern "C" void kernel_launch(void* const* d_in, const int* in_sizes, int n_in,
                              void* d_out, int out_size, void* d_ws, size_t ws_size,
                              hipStream_t stream) {
    (void)in_sizes; (void)n_in; (void)out_size;
    const float* x    = (const float*)d_in[0];
    // d_in[1] x_lengths (all == T), d_in[2] edge_list: unused
    const float* W_ih = (const float*)d_in[3];
    const float* W_hh = (const float*)d_in[4];
    const float* b_ih = (const float*)d_in[5];
    const float* b_hh = (const float*)d_in[6];
    const float* W_fc = (const float*)d_in[7];
    const float* b_fc = (const float*)d_in[8];
    const float* emb  = (const float*)d_in[9];
    float* out = (float*)d_out;

    const size_t gx_bytes = (size_t)BT * 128 * sizeof(float);   // 256 MB
    if (d_ws != nullptr && ws_size >= gx_bytes) {
        float* gx = (float*)d_ws;
        hipLaunchKernelGGL(gx_gemm, dim3(2048), dim3(256), 0, stream,
                           x, W_ih, b_ih, b_hh, gx);
        hipLaunchKernelGGL(ar_decode_pre, dim3(256), dim3(64), 0, stream,
                           gx, W_ih, W_hh, W_fc, b_fc, emb, out);
    } else {
        hipLaunchKernelGGL(ar_decode, dim3(256), dim3(128), 0, stream,
                           x, W_ih, W_hh, b_ih, b_hh, W_fc, b_fc, emb, out);
    }
}

// Round 2
// 1125.272 us; speedup vs baseline: 1.5769x; 1.5769x over previous
//
#include <hip/hip_runtime.h>

// AR LSTM decoder, B=256, T=2048, IN=64, H=32, NCLS=5.
//
// R6: fused producer/consumer again (R5 proved decoupling is neutral for the
// consumer and the gx round-trip costs ~460us -> reverted), with a retimed
// consumer:
//   - classifier for step t-1 is computed at step t IN-LANE from hv (the full
//     h(t-1) vector every lane already reads for the matvec). Each lane owns
//     class lane%5 (32-wide dot, 16 pk_fma); logits broadcast via readlane
//     from lanes 0..4. Replaces 5x wave_sum64 DPP trees (~120 insts, 6-level
//     chain) with ~25 insts and a shallower chain.
//   - log-softmax + store tail placed AFTER the h LDS write so the next
//     step's h read latency is partially hidden under it.
//   - h broadcast via s_hd[64]: all 64 lanes write s_hd[rA] (distinct addrs,
//     2-way bank alias = free), next step reads the even region [0..31].
//   - step 0 peeled (h=0, Ps=0 -> acc = gx directly), final classifier peeled.
// Producer wave: verbatim from the proven kernel.

namespace {

typedef float f2 __attribute__((ext_vector_type(2)));
typedef unsigned int u32;
typedef const __attribute__((address_space(1))) u32* gas_ptr;
typedef __attribute__((address_space(3))) u32* las_ptr;

constexpr int Tn  = 2048;
constexpr int INn = 64;
constexpr int Hn  = 32;
constexpr int NC  = 5;
constexpr int CH  = 32;            // steps per chunk
constexpr int CHF = CH * INn;      // 2048 floats x-chunk (8 KB)
constexpr int GXF = CH * 128;      // 4096 floats gx-chunk (16 KB)
constexpr int NCHUNK = Tn / CH;    // 64

__device__ __forceinline__ float rcpf(float x) { return __builtin_amdgcn_rcpf(x); }
__device__ __forceinline__ float hadd(f2 v) { return v.x + v.y; }

__device__ __forceinline__ float rlane(float x, int l) {
    return __int_as_float(__builtin_amdgcn_readlane(__float_as_int(x), l));
}

__device__ __forceinline__ float dpp_swap1(float x) {   // quad_perm xor 1
    int t = __builtin_amdgcn_update_dpp(0, __float_as_int(x), 0xB1, 0xF, 0xF, true);
    return __int_as_float(t);
}

__device__ __forceinline__ void gl16(const float* g, float* l) {
    __builtin_amdgcn_global_load_lds((gas_ptr)g, (las_ptr)l, 16, 0, 0);
}

__device__ __forceinline__ int ld_acq(int* p) {
    return __hip_atomic_load(p, __ATOMIC_ACQUIRE, __HIP_MEMORY_SCOPE_WORKGROUP);
}
__device__ __forceinline__ void st_rel(int* p, int v) {
    __hip_atomic_store(p, v, __ATOMIC_RELEASE, __HIP_MEMORY_SCOPE_WORKGROUP);
}

__global__ __launch_bounds__(128, 1)
void ar_decode(const float* __restrict__ x,
               const float* __restrict__ W_ih,
               const float* __restrict__ W_hh,
               const float* __restrict__ b_ih,
               const float* __restrict__ b_hh,
               const float* __restrict__ W_fc,
               const float* __restrict__ b_fc,
               const float* __restrict__ emb,
               float* __restrict__ out)
{
    const int b    = blockIdx.x;
    const int tid  = threadIdx.x;
    const int lane = tid & 63;
    const int m    = lane >> 1;
    const int par  = lane & 1;
    const bool even = (par == 0);
    const int rA = par * Hn + m;            // i-row (par0) or f-row (par1)
    const int rB = rA + 2 * Hn;             // g-row (par0) or o-row (par1)

    __shared__ __align__(16) float s_xp[2 * CHF];   // 16 KB x staging
    __shared__ __align__(16) float s_gx[2 * GXF];   // 32 KB gx double buffer
    __shared__ __align__(16) float s_hd[64];        // h duplicated (rA-indexed)
    __shared__ int s_prog;   // chunks produced
    __shared__ int s_cons;   // chunks consumed

    if (tid == 0) { s_prog = 0; s_cons = 0; }
    __syncthreads();

    const float* __restrict__ xb = x + (size_t)b * Tn * INn;

    if (tid >= 64) {
        // ===================== producer wave (verbatim, proven) ==============
        f2 wA[INn / 2], wB[INn / 2];     // 128 VGPR — volatile-pinned loads
        {
            const volatile f2* pA = (const volatile f2*)(W_ih + (size_t)rA * 2 * INn);
            const volatile f2* pB = (const volatile f2*)(W_ih + (size_t)rB * 2 * INn);
            #pragma unroll
            for (int i = 0; i < INn / 2; ++i) { wA[i] = pA[i]; wB[i] = pB[i]; }
        }
        const float biasA = b_ih[rA] + b_hh[rA];
        const float biasB = b_ih[rB] + b_hh[rB];

        #pragma unroll
        for (int r = 0; r < 8; ++r) gl16(xb + r * 256 + lane * 4, s_xp + r * 256);
        #pragma unroll
        for (int r = 0; r < 8; ++r) gl16(xb + CHF + r * 256 + lane * 4, s_xp + CHF + r * 256);

        for (int q = 0; q < NCHUNK; ++q) {
            if (q == NCHUNK - 1) asm volatile("s_waitcnt vmcnt(0)" ::: "memory");
            else                 asm volatile("s_waitcnt vmcnt(8)" ::: "memory");
            while (ld_acq(&s_cons) < q - 1) { }   // gx buf (q&1) free?

            const f2* xc  = (const f2*)(s_xp + (q & 1) * CHF);
            float*    gxd = s_gx + (q & 1) * GXF;
            #pragma unroll 2
            for (int s = 0; s < CH; ++s) {
                const f2* xt2 = xc + s * (INn / 2);
                f2 a0, a1, a2, a3, c0, c1, c2, c3;
                a0 = a1 = a2 = a3 = c0 = c1 = c2 = c3 = (f2)(0.f);
                #pragma unroll
                for (int i = 0; i < INn / 2; i += 4) {
                    const f2 x0 = xt2[i], x1 = xt2[i + 1], x2 = xt2[i + 2], x3 = xt2[i + 3];
                    a0 += wA[i] * x0;     c0 += wB[i] * x0;
                    a1 += wA[i + 1] * x1; c1 += wB[i + 1] * x1;
                    a2 += wA[i + 2] * x2; c2 += wB[i + 2] * x2;
                    a3 += wA[i + 3] * x3; c3 += wB[i + 3] * x3;
                }
                gxd[s * 128 + rA] = biasA + hadd((a0 + a1) + (a2 + a3));
                gxd[s * 128 + rB] = biasB + hadd((c0 + c1) + (c2 + c3));
            }
            if (lane == 0) st_rel(&s_prog, q + 1);   // release: gx drained first
            if (q + 2 < NCHUNK) {                    // refill the freed x buffer
                const float* src = xb + (size_t)(q + 2) * CHF;
                float* dst = s_xp + (q & 1) * CHF;
                #pragma unroll
                for (int r = 0; r < 8; ++r) gl16(src + r * 256 + lane * 4, dst + r * 256);
            }
        }
    } else {
        // ===================== consumer wave (serial chain) ==================
        f2 whA[Hn / 2], whB[Hn / 2];     // 64 VGPR — volatile-pinned loads
        {
            const volatile f2* pA = (const volatile f2*)(W_hh + (size_t)rA * Hn);
            const volatile f2* pB = (const volatile f2*)(W_hh + (size_t)rB * Hn);
            #pragma unroll
            for (int i = 0; i < Hn / 2; ++i) { whA[i] = pA[i]; whB[i] = pB[i]; }
        }

        // P[cls] = ( dot(W_ih[rA,64:128], emb[cls]), dot(W_ih[rB,64:128], emb[cls]) )
        f2 P[NC];
        #pragma unroll
        for (int cls = 0; cls < NC; ++cls) {
            float pa = 0.f, pb = 0.f;
            for (int i = 0; i < INn; ++i) {
                const float e = emb[cls * INn + i];
                pa += W_ih[(size_t)rA * 2 * INn + INn + i] * e;
                pb += W_ih[(size_t)rB * 2 * INn + INn + i] * e;
            }
            f2 v; v.x = pa; v.y = pb; P[cls] = v;
        }

        // per-lane classifier row: class cl = lane % 5 (lanes 0..4 are read)
        const int cl = lane % 5;
        f2 wfcL[Hn / 2];                 // 32 VGPR — volatile-pinned
        {
            const volatile f2* pf = (const volatile f2*)(W_fc + (size_t)cl * Hn);
            #pragma unroll
            for (int i = 0; i < Hn / 2; ++i) wfcL[i] = pf[i];
        }
        const float bfL = b_fc[cl];

        const float zsB  = even ? 2.f : 1.f;   // g: tanh(z) = 2*sig(2z)-1
        const float mulB = even ? 2.f : 1.f;
        const float addB = even ? -1.f : 0.f;

        float* __restrict__ ob = out + (size_t)b * Tn * NC;

        float cst = 0.f;
        f2 Ps; Ps.x = 0.f; Ps.y = 0.f;

        // activations + cell update + h write (identical math to proven kernel)
        auto acts = [&](float accA, float accB) {
            const float actA = rcpf(1.f + __expf(-accA));
            const float sgB  = rcpf(1.f + __expf(-zsB * accB));
            const float actB = fmaf(sgB, mulB, addB);

            const float qA = dpp_swap1(actA);
            const float qB = dpp_swap1(actB);
            const float iv = even ? actA : qA;
            const float fv = even ? qA : actA;
            const float gv = even ? actB : qB;
            const float ov = even ? qB : actB;

            cst = fmaf(fv, cst, iv * gv);
            const float e2 = __expf(2.f * cst);
            const float th = 1.f - 2.f * rcpf(e2 + 1.f);
            const float h  = ov * th;
            s_hd[rA] = h;               // all lanes, distinct addrs (2-way alias)
        };

        // one step t >= 1: classify h(t-1) in-lane, matvec, update, store t-1
        auto full_step = [&](int t, const float* gxc, int s) {
            const float gA = gxc[s * 128 + rA];
            const float gB = gxc[s * 128 + rB];

            const f2* hp = (const f2*)s_hd;   // even region = h(t-1)
            f2 hv[Hn / 2];
            #pragma unroll
            for (int i = 0; i < Hn / 2; ++i) hv[i] = hp[i];

            // ---- classifier for step t-1 (in-lane dot, class = lane%5) ----
            f2 z0, z1, z2, z3;
            z0 = z1 = z2 = z3 = (f2)(0.f);
            #pragma unroll
            for (int i = 0; i < Hn / 2; i += 4) {
                z0 += wfcL[i] * hv[i];         z1 += wfcL[i + 1] * hv[i + 1];
                z2 += wfcL[i + 2] * hv[i + 2]; z3 += wfcL[i + 3] * hv[i + 3];
            }
            const float z = hadd((z0 + z1) + (z2 + z3)) + bfL;
            const float p0 = rlane(z, 0), p1 = rlane(z, 1), p2 = rlane(z, 2),
                        p3 = rlane(z, 3), p4 = rlane(z, 4);

            // argmax (first-max-wins, matches np.argmax)
            float bv = p0; int am = 0;
            bool g1 = p1 > bv; bv = g1 ? p1 : bv; am = g1 ? 1 : am;
            bool g2 = p2 > bv; bv = g2 ? p2 : bv; am = g2 ? 2 : am;
            bool g3 = p3 > bv; bv = g3 ? p3 : bv; am = g3 ? 3 : am;
            bool g4 = p4 > bv; bv = g4 ? p4 : bv; am = g4 ? 4 : am;
            Ps = (am == 0) ? P[0] : (am == 1) ? P[1] : (am == 2) ? P[2]
               : (am == 3) ? P[3] : P[4];

            // ---- W_hh · h(t-1) (identical order to proven kernel) ----
            f2 aA0, aA1, aA2, aA3, aB0, aB1, aB2, aB3;
            aA0 = aA1 = aA2 = aA3 = aB0 = aB1 = aB2 = aB3 = (f2)(0.f);
            #pragma unroll
            for (int i = 0; i < Hn / 2; i += 4) {
                const f2 h0 = hv[i], h1 = hv[i + 1], h3 = hv[i + 2], h4 = hv[i + 3];
                aA0 += whA[i] * h0;     aB0 += whB[i] * h0;
                aA1 += whA[i + 1] * h1; aB1 += whB[i + 1] * h1;
                aA2 += whA[i + 2] * h3; aB2 += whB[i + 2] * h3;
                aA3 += whA[i + 3] * h4; aB3 += whB[i + 3] * h4;
            }
            const float accA = gA + hadd((aA0 + aA1) + (aA2 + aA3)) + Ps.x;
            const float accB = gB + hadd((aB0 + aB1) + (aB2 + aB3)) + Ps.y;

            acts(accA, accB);           // ends with s_hd write of h(t)

            // ---- log-softmax + store for t-1 (off-chain, hides next read) ----
            const float se = __expf(p0 - bv) + __expf(p1 - bv) + __expf(p2 - bv)
                           + __expf(p3 - bv) + __expf(p4 - bv);
            const float lse = bv + __logf(se);
            if (lane < NC) {
                float pv = p0;
                pv = (lane == 1) ? p1 : pv;
                pv = (lane == 2) ? p2 : pv;
                pv = (lane == 3) ? p3 : pv;
                pv = (lane == 4) ? p4 : pv;
                ob[(size_t)(t - 1) * NC + lane] = pv - lse;
            }
        };

        // ---- chunk 0: peel t=0 (h=0, prev=0 -> acc = gx + bias directly) ----
        while (ld_acq(&s_prog) < 1) { }
        {
            const float* gxc = s_gx;
            acts(gxc[rA], gxc[rB]);                 // t = 0
            #pragma unroll 4
            for (int s = 1; s < CH; ++s) full_step(s, gxc, s);
            if (lane == 0) st_rel(&s_cons, 1);
        }
        // ---- chunks 1..63 ----
        for (int q = 1; q < NCHUNK; ++q) {
            while (ld_acq(&s_prog) < q + 1) { }
            const float* gxc = s_gx + (q & 1) * GXF;
            #pragma unroll 4
            for (int s = 0; s < CH; ++s) full_step(q * CH + s, gxc, s);
            if (lane == 0) st_rel(&s_cons, q + 1);
        }
        // ---- epilogue: classifier for t = Tn-1 ----
        {
            const f2* hp = (const f2*)s_hd;
            f2 hv[Hn / 2];
            #pragma unroll
            for (int i = 0; i < Hn / 2; ++i) hv[i] = hp[i];
            f2 z0, z1, z2, z3;
            z0 = z1 = z2 = z3 = (f2)(0.f);
            #pragma unroll
            for (int i = 0; i < Hn / 2; i += 4) {
                z0 += wfcL[i] * hv[i];         z1 += wfcL[i + 1] * hv[i + 1];
                z2 += wfcL[i + 2] * hv[i + 2]; z3 += wfcL[i + 3] * hv[i + 3];
            }
            const float z = hadd((z0 + z1) + (z2 + z3)) + bfL;
            const float p0 = rlane(z, 0), p1 = rlane(z, 1), p2 = rlane(z, 2),
                        p3 = rlane(z, 3), p4 = rlane(z, 4);
            float bv = p0;
            bv = (p1 > bv) ? p1 : bv;
            bv = (p2 > bv) ? p2 : bv;
            bv = (p3 > bv) ? p3 : bv;
            bv = (p4 > bv) ? p4 : bv;
            const float se = __expf(p0 - bv) + __expf(p1 - bv) + __expf(p2 - bv)
                           + __expf(p3 - bv) + __expf(p4 - bv);
            const float lse = bv + __logf(se);
            if (lane < NC) {
                float pv = p0;
                pv = (lane == 1) ? p1 : pv;
                pv = (lane == 2) ? p2 : pv;
                pv = (lane == 3) ? p3 : pv;
                pv = (lane == 4) ? p4 : pv;
                ob[(size_t)(Tn - 1) * NC + lane] = pv - lse;
            }
        }
    }
}

} // namespace

extern "C" void kernel_launch(void* const* d_in, const int* in_sizes, int n_in,
                              void* d_out, int out_size, void* d_ws, size_t ws_size,
                              hipStream_t stream) {
    (void)in_sizes; (void)n_in; (void)d_ws; (void)ws_size; (void)out_size;
    const float* x    = (const float*)d_in[0];
    // d_in[1] x_lengths (all == T), d_in[2] edge_list: unused
    const float* W_ih = (const float*)d_in[3];
    const float* W_hh = (const float*)d_in[4];
    const float* b_ih = (const float*)d_in[5];
    const float* b_hh = (const float*)d_in[6];
    const float* W_fc = (const float*)d_in[7];
    const float* b_fc = (const float*)d_in[8];
    const float* emb  = (const float*)d_in[9];
    float* out = (float*)d_out;

    hipLaunchKernelGGL(ar_decode, dim3(256), dim3(128), 0, stream,
                       x, W_ih, W_hh, b_ih, b_hh, W_fc, b_fc, emb, out);
}